// Round 6
// baseline (573.793 us; speedup 1.0000x reference)
//
#include <hip/hip_runtime.h>
#include <cmath>

#define T_SIZE (1u << 19)

typedef _Float16 h8 __attribute__((ext_vector_type(8)));
typedef _Float16 h4 __attribute__((ext_vector_type(4)));
typedef _Float16 h2 __attribute__((ext_vector_type(2)));
typedef float f4 __attribute__((ext_vector_type(4)));

struct Levels {
    float scale[16];
    int   res[16];
    unsigned dense_mask;
};

// softplus(10z)/10, branch-free
__device__ __forceinline__ float softplus10(float z) {
    float e = __builtin_amdgcn_exp2f(fminf(z * 14.426950408889634f, 126.0f)); // e^{10z}
    return __builtin_amdgcn_logf(1.0f + e) * 0.069314718055994531f;
}

// -------- Kernel 0: table f32 -> f16 (4 entries / thread) ----
__global__ __launch_bounds__(256) void convert_table_kernel(
    const float2* __restrict__ t, h2* __restrict__ o, int total4)
{
    int i = blockIdx.x * 256 + threadIdx.x;
    if (i >= total4) return;
    const float2* src = t + (size_t)i * 4;
    h8 r;
#pragma unroll
    for (int j = 0; j < 4; ++j) {
        float2 v = src[j];
        r[2 * j]     = (_Float16)v.x;
        r[2 * j + 1] = (_Float16)v.y;
    }
    *(h8*)(o + (size_t)i * 4) = r;
}

// ---------------- Kernel A: hash-grid encode -> enc2 [16][N] h2 ----------------
// blockIdx.y = level keeps 1-2 levels hot -> table L2-resident.
// Hash gathers: aligned 8B pair loads, L1-BYPASSED (sc0 via agent-scope atomic
// load) but L2-cached — random gathers have ~0% L1 hit; skip line alloc+fill.
__global__ __launch_bounds__(256) void encode_kernel(
    const float* __restrict__ xs, const h2* __restrict__ table,
    h2* __restrict__ enc2, Levels lv, int N)
{
    __shared__ float sx[768];
    __shared__ float s_scale[16];
    __shared__ int   s_res[16];

    const int i0 = blockIdx.x * 256;
    for (int t = threadIdx.x; t < 768; t += 256) sx[t] = xs[(size_t)i0 * 3 + t];
    if (threadIdx.x < 16) {
        s_scale[threadIdx.x] = lv.scale[threadIdx.x];
        s_res[threadIdx.x]   = lv.res[threadIdx.x];
    }
    __syncthreads();

    const int l = blockIdx.y;
    const int i = i0 + threadIdx.x;
    if (i >= N) return;

    const float px = sx[threadIdx.x * 3 + 0];
    const float py = sx[threadIdx.x * 3 + 1];
    const float pz = sx[threadIdx.x * 3 + 2];
    const float s  = s_scale[l];
    const int  res = s_res[l];

    float fx = px * s + 0.5f, fy = py * s + 0.5f, fz = pz * s + 0.5f;
    float gx = floorf(fx), gy = floorf(fy), gz = floorf(fz);
    float wx = fx - gx, wy = fy - gy, wz = fz - gz;
    int cx = (int)gx, cy = (int)gy, cz = (int)gz;

    const h2* tl = table + (size_t)l * T_SIZE;
    float2 vx0[4], vx1[4];             // combo j: y=(j>>1), z=(j&1)

    if ((lv.dense_mask >> l) & 1u) {   // uniform branch; plain loads (L1 hits real)
        int r1 = res - 1;
        int x0 = min(cx, r1), x1 = min(cx + 1, r1);
        int y0 = min(cy, r1), y1 = min(cy + 1, r1);
        int z0 = min(cz, r1), z1 = min(cz + 1, r1);
        int rr = res * res;
        int bases[4] = {y0 * res + z0 * rr, y0 * res + z1 * rr,
                        y1 * res + z0 * rr, y1 * res + z1 * rr};
#pragma unroll
        for (int j = 0; j < 4; ++j) {
            int idx0 = x0 + bases[j];
            int idx1 = x1 + bases[j];
            h4 pr = *(const h4*)(tl + (idx0 & ~1));   // aligned 8B pair
            float2 lo = make_float2((float)pr[0], (float)pr[1]);
            float2 hi = make_float2((float)pr[2], (float)pr[3]);
            bool hi0 = idx0 & 1;
            vx0[j] = hi0 ? hi : lo;
            if (hi0 && idx1 != idx0) {
                h2 v = tl[idx1];
                vx1[j] = make_float2((float)v[0], (float)v[1]);
            } else {
                vx1[j] = (idx1 == idx0) ? vx0[j] : hi;
            }
        }
    } else {
        unsigned hy0 = (unsigned)cy * 2654435761u, hy1 = (unsigned)(cy + 1) * 2654435761u;
        unsigned hz0 = (unsigned)cz * 805459861u,  hz1 = (unsigned)(cz + 1) * 805459861u;
        unsigned Y[4] = {hy0 ^ hz0, hy0 ^ hz1, hy1 ^ hz0, hy1 ^ hz1};
        const bool odd = (cx & 1);
        const unsigned M = T_SIZE - 1;
#pragma unroll
        for (int j = 0; j < 4; ++j) {
            unsigned h0m = ((unsigned)cx ^ Y[j]) & M;
            unsigned h1m = ((unsigned)(cx + 1) ^ Y[j]) & M;
            unsigned long long praw = __hip_atomic_load(
                (const unsigned long long*)(tl + (h0m & ~1u)),
                __ATOMIC_RELAXED, __HIP_MEMORY_SCOPE_AGENT);      // sc0: skip L1, keep L2
            h4 pr = __builtin_bit_cast(h4, praw);
            float2 lo = make_float2((float)pr[0], (float)pr[1]);
            float2 hi = make_float2((float)pr[2], (float)pr[3]);
            bool h0hi = (h0m & 1u);
            vx0[j] = h0hi ? hi : lo;
            if (odd) {
                unsigned vraw = __hip_atomic_load(
                    (const unsigned*)(tl + h1m),
                    __ATOMIC_RELAXED, __HIP_MEMORY_SCOPE_AGENT);
                h2 v = __builtin_bit_cast(h2, vraw);
                vx1[j] = make_float2((float)v[0], (float)v[1]);
            } else {
                vx1[j] = h0hi ? lo : hi;              // even cx: h1m = h0m ^ 1
            }
        }
    }

    float wx0 = 1.f - wx, wy0 = 1.f - wy, wz0 = 1.f - wz;
    float wyz[4] = {wy0 * wz0, wy0 * wz, wy * wz0, wy * wz};
    float f0 = 0.f, f1 = 0.f;
#pragma unroll
    for (int j = 0; j < 4; ++j) {
        float w0 = wx0 * wyz[j], w1 = wx * wyz[j];
        f0 += w0 * vx0[j].x + w1 * vx1[j].x;
        f1 += w0 * vx0[j].y + w1 * vx1[j].y;
    }

    h2 r;
    r[0] = (_Float16)f0;
    r[1] = (_Float16)f1;
    enc2[(size_t)l * N + i] = r;
}

// ---------------- Kernel B: fused MLP, operand-swapped MFMA ----------------
// Every layer computes D = W · act^T: A = weight frags (global, L2-cached),
// B = activation frags (pt = col). D per lane = 4 consecutive OUT features of
// one point -> epilogue packs to ONE ds_write_b64 per tile (vs 16 b16).
// Next layer's B-frag = contiguous ds_read_b128 from sAct[pt][feat].
// A-layout: A[m=lane&15][k=quad*8+j]; B-layout: B[k=quad*8+j][n=lane&15];
// D-layout: D[row=quad*4+r][col=lane&15].
__global__ __launch_bounds__(256, 4) void mlp_kernel(
    const h2* __restrict__ enc2,
    const float* __restrict__ w1, const float* __restrict__ w2,
    const float* __restrict__ w3, const float* __restrict__ w4,
    float* __restrict__ out, int tiles, int N)
{
    constexpr int AR = 72;                              // 144B rows: 16B-aligned
    __shared__ __align__(16) _Float16 sAct[256 * AR];   // 36864B -> 4 blocks/CU

    const int tid = threadIdx.x;
    const int wave = tid >> 6;
    const int lane = tid & 63;
    const int lrow = lane & 15;
    const int quad = lane >> 4;
    const int waveRow = wave * 64;
    const f4 zero = {0.f, 0.f, 0.f, 0.f};

    // ---- weight A-frags straight from global (once per block, L2-cached) ----
    h8 aW1[4];                                          // [tm], K=32
#pragma unroll
    for (int tm = 0; tm < 4; ++tm) {
        const float* src = w1 + (tm * 16 + lrow) * 32 + quad * 8;
#pragma unroll
        for (int j = 0; j < 8; ++j) aW1[tm][j] = (_Float16)src[j];
    }
    h8 aW2[4][2], aW3[4][2];                            // [tm][km], K=64
#pragma unroll
    for (int tm = 0; tm < 4; ++tm)
#pragma unroll
        for (int km = 0; km < 2; ++km) {
            const float* s2 = w2 + (tm * 16 + lrow) * 64 + km * 32 + quad * 8;
            const float* s3 = w3 + (tm * 16 + lrow) * 64 + km * 32 + quad * 8;
#pragma unroll
            for (int j = 0; j < 8; ++j) {
                aW2[tm][km][j] = (_Float16)s2[j];
                aW3[tm][km][j] = (_Float16)s3[j];
            }
        }
    h8 aW4[2];                                          // one-hot row 0
#pragma unroll
    for (int km = 0; km < 2; ++km)
#pragma unroll
        for (int j = 0; j < 8; ++j)
            aW4[km][j] = (lrow == 0) ? (_Float16)w4[km * 32 + quad * 8 + j]
                                     : (_Float16)0.0f;

    for (int it = 0; it < tiles; ++it) {
        const int blockPt = (blockIdx.x * tiles + it) * 256;

        // ---- Layer 1: D1 = W1 · enc^T ----
#pragma unroll
        for (int t = 0; t < 4; ++t) {
            const int ptg = blockPt + waveRow + t * 16 + lrow;
            h8 b;                                       // B[k=quad*8+j][n=pt]
#pragma unroll
            for (int d = 0; d < 4; ++d) {
                h2 p = enc2[(size_t)(quad * 4 + d) * N + ptg];   // 4B coalesced
                b[2 * d]     = p[0];
                b[2 * d + 1] = p[1];
            }
            const int arow = (waveRow + t * 16 + lrow) * AR;
#pragma unroll
            for (int tm = 0; tm < 4; ++tm) {
                f4 acc = __builtin_amdgcn_mfma_f32_16x16x32_f16(aW1[tm], b, zero, 0, 0, 0);
                h4 pk;
#pragma unroll
                for (int r = 0; r < 4; ++r) pk[r] = (_Float16)softplus10(acc[r]);
                *(h4*)&sAct[arow + tm * 16 + quad * 4] = pk;      // 8B write
            }
        }
        // no barrier: each row pt touched only by lanes of this wave, in order

        // ---- Layers 2 & 3: D = W · act^T ----
#pragma unroll
        for (int layer = 0; layer < 2; ++layer) {
#pragma unroll
            for (int t = 0; t < 4; ++t) {
                const int arow = (waveRow + t * 16 + lrow) * AR;
                h8 b0 = *(const h8*)&sAct[arow + quad * 8];        // k 0..31
                h8 b1 = *(const h8*)&sAct[arow + 32 + quad * 8];   // k 32..63
                f4 accs[4];
#pragma unroll
                for (int tm = 0; tm < 4; ++tm) {
                    f4 acc = __builtin_amdgcn_mfma_f32_16x16x32_f16(
                        layer ? aW3[tm][0] : aW2[tm][0], b0, zero, 0, 0, 0);
                    acc = __builtin_amdgcn_mfma_f32_16x16x32_f16(
                        layer ? aW3[tm][1] : aW2[tm][1], b1, acc, 0, 0, 0);
                    accs[tm] = acc;
                }
                // reads (this instr stream) precede writes -> safe in-place
#pragma unroll
                for (int tm = 0; tm < 4; ++tm) {
                    h4 pk;
#pragma unroll
                    for (int r = 0; r < 4; ++r) pk[r] = (_Float16)softplus10(accs[tm][r]);
                    *(h4*)&sAct[arow + tm * 16 + quad * 4] = pk;
                }
            }
        }

        // ---- Layer 4: D4 = w4(one-hot A) · act3^T, row 0 = result ----
#pragma unroll
        for (int t = 0; t < 4; ++t) {
            const int arow = (waveRow + t * 16 + lrow) * AR;
            h8 b0 = *(const h8*)&sAct[arow + quad * 8];
            h8 b1 = *(const h8*)&sAct[arow + 32 + quad * 8];
            f4 acc = __builtin_amdgcn_mfma_f32_16x16x32_f16(aW4[0], b0, zero, 0, 0, 0);
            acc     = __builtin_amdgcn_mfma_f32_16x16x32_f16(aW4[1], b1, acc,  0, 0, 0);
            if (quad == 0)                                   // D[0][pt] lives in quad 0, r=0
                out[blockPt + waveRow + t * 16 + lrow] = acc[0];
        }
    }
}

// Fallback encode (f32 table) if workspace too small for f16 table
__global__ __launch_bounds__(256) void encode_kernel_f32(
    const float* __restrict__ xs, const float2* __restrict__ table,
    h2* __restrict__ enc2, Levels lv, int N)
{
    const int i = blockIdx.x * 256 + threadIdx.x;
    const int l = blockIdx.y;
    if (i >= N) return;
    float px = xs[3 * i], py = xs[3 * i + 1], pz = xs[3 * i + 2];
    float s = lv.scale[l];
    int res = lv.res[l];
    float fx = px * s + 0.5f, fy = py * s + 0.5f, fz = pz * s + 0.5f;
    float gx = floorf(fx), gy = floorf(fy), gz = floorf(fz);
    float wx = fx - gx, wy = fy - gy, wz = fz - gz;
    int cx = (int)gx, cy = (int)gy, cz = (int)gz;
    unsigned idx[8];
    if ((lv.dense_mask >> l) & 1u) {
        int r1 = res - 1;
        int x0 = min(cx, r1), x1 = min(cx + 1, r1);
        int y0 = min(cy, r1), y1 = min(cy + 1, r1);
        int z0 = min(cz, r1), z1 = min(cz + 1, r1);
        int rr = res * res;
        idx[0] = x0 + y0 * res + z0 * rr; idx[1] = x0 + y0 * res + z1 * rr;
        idx[2] = x0 + y1 * res + z0 * rr; idx[3] = x0 + y1 * res + z1 * rr;
        idx[4] = x1 + y0 * res + z0 * rr; idx[5] = x1 + y0 * res + z1 * rr;
        idx[6] = x1 + y1 * res + z0 * rr; idx[7] = x1 + y1 * res + z1 * rr;
    } else {
        unsigned hx0 = (unsigned)cx, hx1 = (unsigned)(cx + 1);
        unsigned hy0 = (unsigned)cy * 2654435761u, hy1 = (unsigned)(cy + 1) * 2654435761u;
        unsigned hz0 = (unsigned)cz * 805459861u,  hz1 = (unsigned)(cz + 1) * 805459861u;
        idx[0] = (hx0^hy0^hz0) & (T_SIZE-1); idx[1] = (hx0^hy0^hz1) & (T_SIZE-1);
        idx[2] = (hx0^hy1^hz0) & (T_SIZE-1); idx[3] = (hx0^hy1^hz1) & (T_SIZE-1);
        idx[4] = (hx1^hy0^hz0) & (T_SIZE-1); idx[5] = (hx1^hy0^hz1) & (T_SIZE-1);
        idx[6] = (hx1^hy1^hz0) & (T_SIZE-1); idx[7] = (hx1^hy1^hz1) & (T_SIZE-1);
    }
    const float2* tl = table + (size_t)l * T_SIZE;
    float wx0 = 1.f - wx, wy0 = 1.f - wy, wz0 = 1.f - wz;
    float wcs[8] = {wx0*wy0*wz0, wx0*wy0*wz, wx0*wy*wz0, wx0*wy*wz,
                    wx*wy0*wz0,  wx*wy0*wz,  wx*wy*wz0,  wx*wy*wz};
    float f0 = 0.f, f1 = 0.f;
#pragma unroll
    for (int c = 0; c < 8; ++c) {
        float2 v = tl[idx[c]];
        f0 += wcs[c] * v.x; f1 += wcs[c] * v.y;
    }
    h2 r; r[0] = (_Float16)f0; r[1] = (_Float16)f1;
    enc2[(size_t)l * N + i] = r;
}

extern "C" void kernel_launch(void* const* d_in, const int* in_sizes, int n_in,
                              void* d_out, int out_size, void* d_ws, size_t ws_size,
                              hipStream_t stream) {
    const float* x     = (const float*)d_in[0];
    const float* table = (const float*)d_in[1];
    const float* w1    = (const float*)d_in[2];
    const float* w2    = (const float*)d_in[3];
    const float* w3    = (const float*)d_in[4];
    const float* w4    = (const float*)d_in[5];
    float* out = (float*)d_out;
    const int N = in_sizes[0] / 3;                 // 1<<20

    Levels lv;
    lv.dense_mask = 0;
    const double pls = exp2(log2(2048.0 / 16.0) / 15.0);
    const double lg  = log2(pls);
    for (int l = 0; l < 16; ++l) {
        double sc = exp2((double)l * lg) * 16.0 - 1.0;
        int res = (int)ceil(sc) + 1;
        lv.scale[l] = (float)sc;
        lv.res[l]   = res;
        if ((long long)res * res * res <= (long long)T_SIZE) lv.dense_mask |= (1u << l);
    }

    const size_t encBytes   = (size_t)16 * N * 4;        // 64 MB
    const size_t tableBytes = (size_t)16 * T_SIZE * 4;   // 33.5 MB
    h2* enc2 = (h2*)d_ws;

    const int ptBlocks = (N + 255) / 256;                // 4096
    dim3 encGrid(ptBlocks, 16);                          // y = level, slow-varying

    if (ws_size >= encBytes + tableBytes) {
        h2* table16 = (h2*)((char*)d_ws + encBytes);
        const int total4 = 16 * T_SIZE / 4;
        hipLaunchKernelGGL(convert_table_kernel, dim3((total4 + 255) / 256), dim3(256), 0,
                           stream, (const float2*)table, table16, total4);
        hipLaunchKernelGGL(encode_kernel, encGrid, dim3(256), 0, stream,
                           x, (const h2*)table16, enc2, lv, N);
    } else {
        hipLaunchKernelGGL(encode_kernel_f32, encGrid, dim3(256), 0, stream,
                           x, (const float2*)table, enc2, lv, N);
    }

    const int mlpBlocks = 1024;                          // 4 blocks/CU (LDS-capped)
    const int tiles = N / 256 / mlpBlocks;               // 4
    hipLaunchKernelGGL(mlp_kernel, dim3(mlpBlocks), dim3(256), 0, stream,
                       enc2, w1, w2, w3, w4, out, tiles, N);
}

// Round 7
// 537.173 us; speedup vs baseline: 1.0682x; 1.0682x over previous
//
#include <hip/hip_runtime.h>
#include <cmath>

#define T_SIZE (1u << 19)

typedef _Float16 h8 __attribute__((ext_vector_type(8)));
typedef _Float16 h4 __attribute__((ext_vector_type(4)));
typedef _Float16 h2 __attribute__((ext_vector_type(2)));
typedef float f4 __attribute__((ext_vector_type(4)));

struct Levels {
    float scale[16];
    int   res[16];
    unsigned dense_mask;
};

// softplus(10z)/10, branch-free
__device__ __forceinline__ float softplus10(float z) {
    float e = __builtin_amdgcn_exp2f(fminf(z * 14.426950408889634f, 126.0f)); // e^{10z}
    return __builtin_amdgcn_logf(1.0f + e) * 0.069314718055994531f;
}

// -------- Kernel 0: table f32 -> f16 (4 entries / thread) ----
__global__ __launch_bounds__(256) void convert_table_kernel(
    const float2* __restrict__ t, h2* __restrict__ o, int total4)
{
    int i = blockIdx.x * 256 + threadIdx.x;
    if (i >= total4) return;
    const float2* src = t + (size_t)i * 4;
    h8 r;
#pragma unroll
    for (int j = 0; j < 4; ++j) {
        float2 v = src[j];
        r[2 * j]     = (_Float16)v.x;
        r[2 * j + 1] = (_Float16)v.y;
    }
    *(h8*)(o + (size_t)i * 4) = r;
}

// ---------------- Kernel A: hash-grid encode -> enc2 [16][N] h2 ----------------
// blockIdx.y = level (slow-varying) keeps 1-2 levels hot -> table L2-resident.
// Aligned 8B pair loads (x-corners differ by ^1 hash / +1 dense) minimize the
// divergent-address count — the measured limiter (~3.3 cyc per missed line).
__global__ __launch_bounds__(256) void encode_kernel(
    const float* __restrict__ xs, const h2* __restrict__ table,
    h2* __restrict__ enc2, Levels lv, int N)
{
    __shared__ float sx[768];
    __shared__ float s_scale[16];
    __shared__ int   s_res[16];

    const int i0 = blockIdx.x * 256;
    for (int t = threadIdx.x; t < 768; t += 256) sx[t] = xs[(size_t)i0 * 3 + t];
    if (threadIdx.x < 16) {
        s_scale[threadIdx.x] = lv.scale[threadIdx.x];
        s_res[threadIdx.x]   = lv.res[threadIdx.x];
    }
    __syncthreads();

    const int l = blockIdx.y;
    const int i = i0 + threadIdx.x;
    if (i >= N) return;

    const float px = sx[threadIdx.x * 3 + 0];
    const float py = sx[threadIdx.x * 3 + 1];
    const float pz = sx[threadIdx.x * 3 + 2];
    const float s  = s_scale[l];
    const int  res = s_res[l];

    float fx = px * s + 0.5f, fy = py * s + 0.5f, fz = pz * s + 0.5f;
    float gx = floorf(fx), gy = floorf(fy), gz = floorf(fz);
    float wx = fx - gx, wy = fy - gy, wz = fz - gz;
    int cx = (int)gx, cy = (int)gy, cz = (int)gz;

    const h2* tl = table + (size_t)l * T_SIZE;
    float2 vx0[4], vx1[4];             // combo j: y=(j>>1), z=(j&1)

    if ((lv.dense_mask >> l) & 1u) {   // uniform branch
        int r1 = res - 1;
        int x0 = min(cx, r1), x1 = min(cx + 1, r1);
        int y0 = min(cy, r1), y1 = min(cy + 1, r1);
        int z0 = min(cz, r1), z1 = min(cz + 1, r1);
        int rr = res * res;
        int bases[4] = {y0 * res + z0 * rr, y0 * res + z1 * rr,
                        y1 * res + z0 * rr, y1 * res + z1 * rr};
#pragma unroll
        for (int j = 0; j < 4; ++j) {
            int idx0 = x0 + bases[j];
            int idx1 = x1 + bases[j];
            h4 pr = *(const h4*)(tl + (idx0 & ~1));   // aligned 8B pair
            float2 lo = make_float2((float)pr[0], (float)pr[1]);
            float2 hi = make_float2((float)pr[2], (float)pr[3]);
            bool hi0 = idx0 & 1;
            vx0[j] = hi0 ? hi : lo;
            if (hi0 && idx1 != idx0) {
                h2 v = tl[idx1];
                vx1[j] = make_float2((float)v[0], (float)v[1]);
            } else {
                vx1[j] = (idx1 == idx0) ? vx0[j] : hi;
            }
        }
    } else {
        unsigned hy0 = (unsigned)cy * 2654435761u, hy1 = (unsigned)(cy + 1) * 2654435761u;
        unsigned hz0 = (unsigned)cz * 805459861u,  hz1 = (unsigned)(cz + 1) * 805459861u;
        unsigned Y[4] = {hy0 ^ hz0, hy0 ^ hz1, hy1 ^ hz0, hy1 ^ hz1};
        const bool odd = (cx & 1);
        const unsigned M = T_SIZE - 1;
#pragma unroll
        for (int j = 0; j < 4; ++j) {
            unsigned h0m = ((unsigned)cx ^ Y[j]) & M;
            unsigned h1m = ((unsigned)(cx + 1) ^ Y[j]) & M;
            h4 pr = *(const h4*)(tl + (h0m & ~1u));   // aligned 8B pair
            float2 lo = make_float2((float)pr[0], (float)pr[1]);
            float2 hi = make_float2((float)pr[2], (float)pr[3]);
            bool h0hi = (h0m & 1u);
            vx0[j] = h0hi ? hi : lo;
            if (odd) {
                h2 v = tl[h1m];
                vx1[j] = make_float2((float)v[0], (float)v[1]);
            } else {
                vx1[j] = h0hi ? lo : hi;              // even cx: h1m = h0m ^ 1
            }
        }
    }

    float wx0 = 1.f - wx, wy0 = 1.f - wy, wz0 = 1.f - wz;
    float wyz[4] = {wy0 * wz0, wy0 * wz, wy * wz0, wy * wz};
    float f0 = 0.f, f1 = 0.f;
#pragma unroll
    for (int j = 0; j < 4; ++j) {
        float w0 = wx0 * wyz[j], w1 = wx * wyz[j];
        f0 += w0 * vx0[j].x + w1 * vx1[j].x;
        f1 += w0 * vx0[j].y + w1 * vx1[j].y;
    }

    h2 r;
    r[0] = (_Float16)f0;
    r[1] = (_Float16)f1;
    enc2[(size_t)l * N + i] = r;
}

// ---------------- Kernel B: fused MLP, operand-swapped MFMA ----------------
// D = W · act^T per layer: A = weight frags (regs), B = activation frags.
// D per lane = 4 consecutive OUT features of one point -> h4 LDS writes.
// Layer 4 fused into layer 3's register epilogue (w4-weighted softplus dot +
// shfl_xor reduce) -> no layer-3 LDS write, no L4 MFMA/LDS at all.
// LB(256,3): cap 170 VGPR — R6's LB(256,4) spilled (88 pinned weight VGPRs).
// A-layout: A[m=lane&15][k=quad*8+j]; B[k=quad*8+j][n=lane&15];
// D[row=quad*4+r][col=lane&15].
__global__ __launch_bounds__(256, 3) void mlp_kernel(
    const h2* __restrict__ enc2,
    const float* __restrict__ w1, const float* __restrict__ w2,
    const float* __restrict__ w3, const float* __restrict__ w4,
    float* __restrict__ out, int nTiles, int N)
{
    constexpr int AR = 72;                              // 144B rows, 16B-aligned
    __shared__ __align__(16) _Float16 sAct[256 * AR];   // 36864B

    const int tid = threadIdx.x;
    const int wave = tid >> 6;
    const int lane = tid & 63;
    const int lrow = lane & 15;
    const int quad = lane >> 4;
    const int waveRow = wave * 64;
    const f4 zero = {0.f, 0.f, 0.f, 0.f};

    // ---- weight A-frags from global, once per block (L2-cached) ----
    h8 aW1[4];
#pragma unroll
    for (int tm = 0; tm < 4; ++tm) {
        const float* src = w1 + (tm * 16 + lrow) * 32 + quad * 8;
#pragma unroll
        for (int j = 0; j < 8; ++j) aW1[tm][j] = (_Float16)src[j];
    }
    h8 aW2[4][2], aW3[4][2];
#pragma unroll
    for (int tm = 0; tm < 4; ++tm)
#pragma unroll
        for (int km = 0; km < 2; ++km) {
            const float* s2 = w2 + (tm * 16 + lrow) * 64 + km * 32 + quad * 8;
            const float* s3 = w3 + (tm * 16 + lrow) * 64 + km * 32 + quad * 8;
#pragma unroll
            for (int j = 0; j < 8; ++j) {
                aW2[tm][km][j] = (_Float16)s2[j];
                aW3[tm][km][j] = (_Float16)s3[j];
            }
        }
    // w4 entries for the 16 features this lane's D-regs hold (uniform in lrow)
    float w4f[16];
#pragma unroll
    for (int tm = 0; tm < 4; ++tm)
#pragma unroll
        for (int r = 0; r < 4; ++r)
            w4f[tm * 4 + r] = w4[tm * 16 + quad * 4 + r];

    for (int tile = blockIdx.x; tile < nTiles; tile += gridDim.x) {
        const int blockPt = tile * 256;

        // ---- Layer 1: D1 = W1 · enc^T ----
#pragma unroll
        for (int t = 0; t < 4; ++t) {
            const int ptg = blockPt + waveRow + t * 16 + lrow;
            h8 b;
#pragma unroll
            for (int d = 0; d < 4; ++d) {
                h2 p = enc2[(size_t)(quad * 4 + d) * N + ptg];   // 4B coalesced
                b[2 * d]     = p[0];
                b[2 * d + 1] = p[1];
            }
            const int arow = (waveRow + t * 16 + lrow) * AR;
#pragma unroll
            for (int tm = 0; tm < 4; ++tm) {
                f4 acc = __builtin_amdgcn_mfma_f32_16x16x32_f16(aW1[tm], b, zero, 0, 0, 0);
                h4 pk;
#pragma unroll
                for (int r = 0; r < 4; ++r) pk[r] = (_Float16)softplus10(acc[r]);
                *(h4*)&sAct[arow + tm * 16 + quad * 4] = pk;     // 8B write
            }
        }
        // no barriers anywhere: same-wave LDS ops execute in order

        // ---- Layer 2: D2 = W2 · act1^T ----
#pragma unroll
        for (int t = 0; t < 4; ++t) {
            const int arow = (waveRow + t * 16 + lrow) * AR;
            h8 b0 = *(const h8*)&sAct[arow + quad * 8];
            h8 b1 = *(const h8*)&sAct[arow + 32 + quad * 8];
            f4 accs[4];
#pragma unroll
            for (int tm = 0; tm < 4; ++tm) {
                f4 acc = __builtin_amdgcn_mfma_f32_16x16x32_f16(aW2[tm][0], b0, zero, 0, 0, 0);
                acc     = __builtin_amdgcn_mfma_f32_16x16x32_f16(aW2[tm][1], b1, acc,  0, 0, 0);
                accs[tm] = acc;
            }
#pragma unroll
            for (int tm = 0; tm < 4; ++tm) {
                h4 pk;
#pragma unroll
                for (int r = 0; r < 4; ++r) pk[r] = (_Float16)softplus10(accs[tm][r]);
                *(h4*)&sAct[arow + tm * 16 + quad * 4] = pk;
            }
        }

        // ---- Layer 3 + Layer 4 fused: sdf = w4 · softplus(W3 · act2^T) ----
#pragma unroll
        for (int t = 0; t < 4; ++t) {
            const int arow = (waveRow + t * 16 + lrow) * AR;
            h8 b0 = *(const h8*)&sAct[arow + quad * 8];
            h8 b1 = *(const h8*)&sAct[arow + 32 + quad * 8];
            float sum = 0.f;
#pragma unroll
            for (int tm = 0; tm < 4; ++tm) {
                f4 acc = __builtin_amdgcn_mfma_f32_16x16x32_f16(aW3[tm][0], b0, zero, 0, 0, 0);
                acc     = __builtin_amdgcn_mfma_f32_16x16x32_f16(aW3[tm][1], b1, acc,  0, 0, 0);
#pragma unroll
                for (int r = 0; r < 4; ++r)
                    sum += w4f[tm * 4 + r] * softplus10(acc[r]);
            }
            sum += __shfl_xor(sum, 16, 64);   // reduce across the 4 quads
            sum += __shfl_xor(sum, 32, 64);
            if (quad == 0)
                out[blockPt + waveRow + t * 16 + lrow] = sum;
        }
    }
}

// Fallback encode (f32 table) if workspace too small for f16 table
__global__ __launch_bounds__(256) void encode_kernel_f32(
    const float* __restrict__ xs, const float2* __restrict__ table,
    h2* __restrict__ enc2, Levels lv, int N)
{
    const int i = blockIdx.x * 256 + threadIdx.x;
    const int l = blockIdx.y;
    if (i >= N) return;
    float px = xs[3 * i], py = xs[3 * i + 1], pz = xs[3 * i + 2];
    float s = lv.scale[l];
    int res = lv.res[l];
    float fx = px * s + 0.5f, fy = py * s + 0.5f, fz = pz * s + 0.5f;
    float gx = floorf(fx), gy = floorf(fy), gz = floorf(fz);
    float wx = fx - gx, wy = fy - gy, wz = fz - gz;
    int cx = (int)gx, cy = (int)gy, cz = (int)gz;
    unsigned idx[8];
    if ((lv.dense_mask >> l) & 1u) {
        int r1 = res - 1;
        int x0 = min(cx, r1), x1 = min(cx + 1, r1);
        int y0 = min(cy, r1), y1 = min(cy + 1, r1);
        int z0 = min(cz, r1), z1 = min(cz + 1, r1);
        int rr = res * res;
        idx[0] = x0 + y0 * res + z0 * rr; idx[1] = x0 + y0 * res + z1 * rr;
        idx[2] = x0 + y1 * res + z0 * rr; idx[3] = x0 + y1 * res + z1 * rr;
        idx[4] = x1 + y0 * res + z0 * rr; idx[5] = x1 + y0 * res + z1 * rr;
        idx[6] = x1 + y1 * res + z0 * rr; idx[7] = x1 + y1 * res + z1 * rr;
    } else {
        unsigned hx0 = (unsigned)cx, hx1 = (unsigned)(cx + 1);
        unsigned hy0 = (unsigned)cy * 2654435761u, hy1 = (unsigned)(cy + 1) * 2654435761u;
        unsigned hz0 = (unsigned)cz * 805459861u,  hz1 = (unsigned)(cz + 1) * 805459861u;
        idx[0] = (hx0^hy0^hz0) & (T_SIZE-1); idx[1] = (hx0^hy0^hz1) & (T_SIZE-1);
        idx[2] = (hx0^hy1^hz0) & (T_SIZE-1); idx[3] = (hx0^hy1^hz1) & (T_SIZE-1);
        idx[4] = (hx1^hy0^hz0) & (T_SIZE-1); idx[5] = (hx1^hy0^hz1) & (T_SIZE-1);
        idx[6] = (hx1^hy1^hz0) & (T_SIZE-1); idx[7] = (hx1^hy1^hz1) & (T_SIZE-1);
    }
    const float2* tl = table + (size_t)l * T_SIZE;
    float wx0 = 1.f - wx, wy0 = 1.f - wy, wz0 = 1.f - wz;
    float wcs[8] = {wx0*wy0*wz0, wx0*wy0*wz, wx0*wy*wz0, wx0*wy*wz,
                    wx*wy0*wz0,  wx*wy0*wz,  wx*wy*wz0,  wx*wy*wz};
    float f0 = 0.f, f1 = 0.f;
#pragma unroll
    for (int c = 0; c < 8; ++c) {
        float2 v = tl[idx[c]];
        f0 += wcs[c] * v.x; f1 += wcs[c] * v.y;
    }
    h2 r; r[0] = (_Float16)f0; r[1] = (_Float16)f1;
    enc2[(size_t)l * N + i] = r;
}

extern "C" void kernel_launch(void* const* d_in, const int* in_sizes, int n_in,
                              void* d_out, int out_size, void* d_ws, size_t ws_size,
                              hipStream_t stream) {
    const float* x     = (const float*)d_in[0];
    const float* table = (const float*)d_in[1];
    const float* w1    = (const float*)d_in[2];
    const float* w2    = (const float*)d_in[3];
    const float* w3    = (const float*)d_in[4];
    const float* w4    = (const float*)d_in[5];
    float* out = (float*)d_out;
    const int N = in_sizes[0] / 3;                 // 1<<20

    Levels lv;
    lv.dense_mask = 0;
    const double pls = exp2(log2(2048.0 / 16.0) / 15.0);
    const double lg  = log2(pls);
    for (int l = 0; l < 16; ++l) {
        double sc = exp2((double)l * lg) * 16.0 - 1.0;
        int res = (int)ceil(sc) + 1;
        lv.scale[l] = (float)sc;
        lv.res[l]   = res;
        if ((long long)res * res * res <= (long long)T_SIZE) lv.dense_mask |= (1u << l);
    }

    const size_t encBytes   = (size_t)16 * N * 4;        // 64 MB
    const size_t tableBytes = (size_t)16 * T_SIZE * 4;   // 33.5 MB
    h2* enc2 = (h2*)d_ws;

    const int ptBlocks = (N + 255) / 256;                // 4096
    dim3 encGrid(ptBlocks, 16);                          // y = level, slow-varying

    if (ws_size >= encBytes + tableBytes) {
        h2* table16 = (h2*)((char*)d_ws + encBytes);
        const int total4 = 16 * T_SIZE / 4;
        hipLaunchKernelGGL(convert_table_kernel, dim3((total4 + 255) / 256), dim3(256), 0,
                           stream, (const float2*)table, table16, total4);
        hipLaunchKernelGGL(encode_kernel, encGrid, dim3(256), 0, stream,
                           x, (const h2*)table16, enc2, lv, N);
    } else {
        hipLaunchKernelGGL(encode_kernel_f32, encGrid, dim3(256), 0, stream,
                           x, (const float2*)table, enc2, lv, N);
    }

    const int nTiles = N / 256;                          // 4096
    const int mlpBlocks = 768;                           // 3 blocks/CU, grid-stride
    hipLaunchKernelGGL(mlp_kernel, dim3(mlpBlocks), dim3(256), 0, stream,
                       enc2, w1, w2, w3, w4, out, nTiles, N);
}